// Round 1
// 183.613 us; speedup vs baseline: 1.0378x; 1.0378x over previous
//
#include <hip/hip_runtime.h>
#include <math.h>

#define DIM 192
#define OD  191          // output domain per axis
#define VOL 7077888      // 192^3
#define TW  14           // tile width  (w)  -> 16-lane DPP row covers 16-wide halo
#define TH  16           // tile height (h)
#define CD  24           // d-planes per chunk
#define NBW 14           // ceil(191/14)
#define NBH 12           // ceil(191/16)
#define NCH 8            // 8*24 = 192 >= 191

typedef float    f4 __attribute__((ext_vector_type(4)));
typedef _Float16 h8 __attribute__((ext_vector_type(8)));
typedef _Float16 h2 __attribute__((ext_vector_type(2)));

template<int CTRL>
__device__ __forceinline__ int dppi(int x) {
    // bound_ctrl=true: out-of-row source reads as 0 (matches zero padding)
    return __builtin_amdgcn_update_dpp(0, x, CTRL, 0xF, 0xF, true);
}

union U8 { h8 v; int i[4]; };
union U2 { h2 v; int i; };

// Symmetric 3-tap w-window sum across a 16-lane DPP row:
//   out(lane) = in(lane-1) + in(lane) + in(lane+1), 0 outside the row.
// Uses row_shl:1 + row_shr:1 so the result is direction-convention-proof.
__device__ __forceinline__ void wsum3(h8& a, h2& b) {
    U8 ua, s1, s2;
    ua.v = a;
    #pragma unroll
    for (int k = 0; k < 4; ++k) {
        s1.i[k] = dppi<0x101>(ua.i[k]);   // row_shl:1
        s2.i[k] = dppi<0x111>(ua.i[k]);   // row_shr:1
    }
    a = ua.v + s1.v + s2.v;
    U2 ub, t1, t2;
    ub.v = b;
    t1.i = dppi<0x101>(ub.i);
    t2.i = dppi<0x111>(ub.i);
    b = ub.v + t1.v + t2.v;
}

__device__ __forceinline__ void make_diff(const f4 c, const f4 cw, const f4 ch, const f4 cd,
                                          h8& va, h2& vb) {
    const float hx  = fabsf(ch.x - c.x), hy  = fabsf(ch.y - c.y), hz  = fabsf(ch.z - c.z);
    const float dx_ = fabsf(cd.x - c.x), dy_ = fabsf(cd.y - c.y), dz_ = fabsf(cd.z - c.z);
    const float wx  = fabsf(cw.x - c.x), wy  = fabsf(cw.y - c.y), wz  = fabsf(cw.z - c.z);
    va = (h8){(_Float16)hx,  (_Float16)hy,  (_Float16)hz,
              (_Float16)dx_, (_Float16)dy_, (_Float16)dz_,
              (_Float16)wx,  (_Float16)wy};
    vb = (h2){(_Float16)wz, (_Float16)0.f};
}

// Fused: diff -> separable 3x3x3 box mean (w: DPP in-register, h: LDS 3-tap,
// z: register ring) -> neo-hookean energy -> mean reduction.
// LDS traffic per point drops from ~14xb128+9xb32 reads to ~5.5xb128+3xb32:
// the 9-tap window gather is gone; c/cd raw values ride in registers.
__global__ __launch_bounds__(256, 6)
void nh_fused_kernel(const float* __restrict__ P, float* __restrict__ out) {
    const int tid = threadIdx.x;
    const int tx  = tid & 15;        // lane within DPP row == w within halo
    const int ty  = tid >> 4;        // h within tile
    const int w0  = blockIdx.x * TW;
    const int h0  = blockIdx.y * TH;
    const int ds  = blockIdx.z * CD;
    const int de  = min(ds + CD, OD);

    __shared__ f4 sraw[2][19][18];   // raw y_pred ring, rows h0-1..h0+17, cols w0-1..w0+15 (pad 18)
    __shared__ h8 sW[18][16];        // w-summed diffs {Hd0,Hd1,Hd2,Dd0,Dd1,Dd2,Wd0,Wd1}
    __shared__ h2 sWB[18][16];       // w-summed {Wd2, 0}
    __shared__ float wsum[4];

    const bool valid = (tx < TW) && (w0 + tx < OD) && (h0 + ty < OD);

    h8 a0 = (h8)0, a1 = (h8)0, a2 = (h8)0;
    h2 b0 = (h2)0, b1 = (h2)0, b2 = (h2)0;
    f4 cur = (f4)0, prev = (f4)0;    // this thread's staged raw at (t, h0-1+ty, w0-1+tx) and t-1
    float acc = 0.f;

    for (int t = ds - 1; t <= de + 1; ++t) {
        const int cb = t & 1, pb = cb ^ 1;

        // (a) stage raw plane t into LDS ring; primary point kept in register
        if (t >= 0 && t < DIM) {
            {   // primary: (hh=ty, ww=tx) -- matches the build pass-1 mapping
                const int hp = h0 - 1 + ty;
                const int wp = w0 - 1 + tx;
                f4 r = (f4)0;
                if (hp >= 0 && hp < DIM && wp >= 0 && wp < DIM) {
                    const size_t base = ((size_t)t * DIM + (size_t)hp) * DIM + (size_t)wp;
                    r.x = P[base];
                    r.y = P[base + VOL];
                    r.z = P[base + 2 * VOL];
                }
                sraw[cb][ty][tx] = r;
                cur = r;
            }
            // leftovers: col 16 (rows 0..15) + rows 16..18 (cols 0..16) = 67 items
            if (tid < 67) {
                int hh, ww;
                if (tid < 16) { hh = tid; ww = 16; }
                else { const int l = tid - 16; const int q = l / 17; hh = 16 + q; ww = l - 17 * q; }
                const int hp = h0 - 1 + hh;
                const int wp = w0 - 1 + ww;
                f4 r = (f4)0;
                if (hp >= 0 && hp < DIM && wp >= 0 && wp < DIM) {
                    const size_t base = ((size_t)t * DIM + (size_t)hp) * DIM + (size_t)wp;
                    r.x = P[base];
                    r.y = P[base + VOL];
                    r.z = P[base + 2 * VOL];
                }
                sraw[cb][hh][ww] = r;
            }
        } else {
            cur = (f4)0;
        }
        __syncthreads();

        // (b) build w-summed diff plane p = t-1 into sW/sWB
        const int p = t - 1;
        const bool built = (p >= 0) && (p < OD) && (t >= ds);   // wave-uniform

        {   // pass 1: rows 0..15 (rr=ty, lane=tx); c,cd from registers
            h8 sa = (h8)0; h2 sb = (h2)0;
            if (built) {
                const int hp = h0 - 1 + ty;
                const int wp = w0 - 1 + tx;
                h8 va = (h8)0; h2 vb = (h2)0;
                if (hp >= 0 && hp < OD && wp >= 0 && wp < OD) {
                    const f4 c  = prev;                      // (p, hp, wp)   from register
                    const f4 cw = sraw[pb][ty][tx + 1];      // (p, hp, wp+1)
                    const f4 ch = sraw[pb][ty + 1][tx];      // (p, hp+1, wp)
                    const f4 cd = cur;                       // (p+1, hp, wp) from register
                    make_diff(c, cw, ch, cd, va, vb);
                }
                wsum3(va, vb);                               // all lanes participate
                sa = va; sb = vb;
            }
            sW[ty][tx] = sa; sWB[ty][tx] = sb;
        }
        if (tid < 32) {  // pass 2: rows 16,17 (wave 0 only; DPP rows fully active)
            const int rr   = 16 + (tid >> 4);
            const int lane = tid & 15;
            h8 sa = (h8)0; h2 sb = (h2)0;
            if (built) {
                const int hp = h0 - 1 + rr;
                const int wp = w0 - 1 + lane;
                h8 va = (h8)0; h2 vb = (h2)0;
                if (hp >= 0 && hp < OD && wp >= 0 && wp < OD) {
                    const f4 c  = sraw[pb][rr][lane];
                    const f4 cw = sraw[pb][rr][lane + 1];
                    const f4 ch = sraw[pb][rr + 1][lane];
                    const f4 cd = sraw[cb][rr][lane];
                    make_diff(c, cw, ch, cd, va, vb);
                }
                wsum3(va, vb);
                sa = va; sb = vb;
            }
            sW[rr][lane] = sa; sWB[rr][lane] = sb;
        }
        __syncthreads();

        // (c) h-window 3-tap, rotate z-ring, emit d = t-2
        a0 = a1; a1 = a2; b0 = b1; b1 = b2;
        {
            const int cc = (tx + 1) & 15;   // symmetric w-sum center; tx=15 clamped (discarded)
            a2 = sW[ty][cc] + sW[ty + 1][cc] + sW[ty + 2][cc];
            b2 = sWB[ty][cc] + sWB[ty + 1][cc] + sWB[ty + 2][cc];
        }

        const int d = t - 2;
        if (valid && d >= ds && d < de) {
            const h8 FA = a0 + a1 + a2;
            const h2 FB = b0 + b1 + b2;
            const float inv27 = 1.f / 27.f;
            const float dydx = (float)FA[0] * inv27, dxdx = (float)FA[1] * inv27, dzdx = (float)FA[2] * inv27;
            const float dydy = (float)FA[3] * inv27, dxdy = (float)FA[4] * inv27, dzdy = (float)FA[5] * inv27;
            const float dydz = (float)FA[6] * inv27, dxdz = (float)FA[7] * inv27, dzdz = (float)FB[0] * inv27;
            const float a = dxdx + 1.f, e = dydy + 1.f, iN = dzdz + 1.f;
            const float J = a * (e * iN - dydz * dzdy)
                          - dxdy * (dydx * iN - dydz * dzdx)
                          + dxdz * (dydx * dzdy - e * dzdx);
            const float Tr = a * a + dxdy * dxdy + dxdz * dxdz
                           + dydx * dydx + e * e + dydz * dydz
                           + dzdx * dzdx + dzdy * dzdy + iN * iN;
            const float stretch = Tr * expf(1.f - J) - 3.f;
            const float vol = (J - 1.f) * (J - 1.f);
            // mu=1,lam=5 -> U = (1/12)*stretch + (15/31)*vol (verified exact in prior session)
            acc += 0.0833333358f * stretch + 0.4838709677f * vol;
        }

        prev = cur;
    }

    // mean scaling (191^3)
    acc *= (1.f / 6967871.f);

    // wave reduce (64 lanes), then block reduce, one atomic per block
    #pragma unroll
    for (int off = 32; off > 0; off >>= 1) acc += __shfl_down(acc, off, 64);
    if ((tid & 63) == 0) wsum[tid >> 6] = acc;
    __syncthreads();
    if (tid == 0) {
        atomicAdd(out, wsum[0] + wsum[1] + wsum[2] + wsum[3]);
    }
}

extern "C" void kernel_launch(void* const* d_in, const int* in_sizes, int n_in,
                              void* d_out, int out_size, void* d_ws, size_t ws_size,
                              hipStream_t stream) {
    const float* y_pred = (const float*)d_in[0];
    float* out = (float*)d_out;

    // d_out is poisoned 0xAA before every timed launch — zero it (graph-capturable).
    hipMemsetAsync(out, 0, sizeof(float), stream);

    dim3 grid(NBW, NBH, NCH);
    nh_fused_kernel<<<grid, 256, 0, stream>>>(y_pred, out);
}

// Round 2
// 173.624 us; speedup vs baseline: 1.0975x; 1.0575x over previous
//
#include <hip/hip_runtime.h>
#include <math.h>

#define DIM 192
#define OD  191          // output domain per axis
#define PLANE 36864      // 192*192
#define VOL 7077888      // 192^3
#define TW  14           // tile width  (w)  -> 16-lane DPP row covers 16-wide halo
#define TH  16           // tile height (h)
#define CD  16           // d-planes per chunk
#define NBW 14           // ceil(191/14)
#define NBH 12           // ceil(191/16)
#define NCH 12           // 12*16 = 192 >= 191

typedef float    f4 __attribute__((ext_vector_type(4)));
typedef _Float16 h8 __attribute__((ext_vector_type(8)));
typedef _Float16 h2 __attribute__((ext_vector_type(2)));

template<int CTRL>
__device__ __forceinline__ int dppi(int x) {
    // bound_ctrl=true: out-of-row source reads as 0 (matches zero padding)
    return __builtin_amdgcn_update_dpp(0, x, CTRL, 0xF, 0xF, true);
}

union U8 { h8 v; int i[4]; };
union U2 { h2 v; int i; };

// Symmetric 3-tap w-window sum across a 16-lane DPP row:
//   out(lane) = in(lane-1) + in(lane) + in(lane+1), 0 outside the row.
__device__ __forceinline__ void wsum3(h8& a, h2& b) {
    U8 ua, s1, s2;
    ua.v = a;
    #pragma unroll
    for (int k = 0; k < 4; ++k) {
        s1.i[k] = dppi<0x101>(ua.i[k]);   // row_shl:1
        s2.i[k] = dppi<0x111>(ua.i[k]);   // row_shr:1
    }
    a = ua.v + s1.v + s2.v;
    U2 ub, t1, t2;
    ub.v = b;
    t1.i = dppi<0x101>(ub.i);
    t2.i = dppi<0x111>(ub.i);
    b = ub.v + t1.v + t2.v;
}

__device__ __forceinline__ void make_diff(const f4 c, const f4 cw, const f4 ch, const f4 cd,
                                          h8& va, h2& vb) {
    const float hx  = fabsf(ch.x - c.x), hy  = fabsf(ch.y - c.y), hz  = fabsf(ch.z - c.z);
    const float dx_ = fabsf(cd.x - c.x), dy_ = fabsf(cd.y - c.y), dz_ = fabsf(cd.z - c.z);
    const float wx  = fabsf(cw.x - c.x), wy  = fabsf(cw.y - c.y), wz  = fabsf(cw.z - c.z);
    va = (h8){(_Float16)hx,  (_Float16)hy,  (_Float16)hz,
              (_Float16)dx_, (_Float16)dy_, (_Float16)dz_,
              (_Float16)wx,  (_Float16)wy};
    vb = (h2){(_Float16)wz, (_Float16)0.f};
}

__device__ __forceinline__ f4 ld3(const float* __restrict__ P, int idx, bool ok) {
    f4 r = (f4)0;
    if (ok) {
        r.x = P[idx];
        r.y = P[idx + VOL];
        r.z = P[idx + 2 * VOL];
    }
    return r;
}

// Fused: diff -> separable 3x3x3 box mean (w: DPP, h: LDS 3-tap, z: register
// ring) -> neo-hookean energy -> mean reduction.
// Round-2 structure: software-pipelined plane loads (prefetch t+1 into regs
// while computing t) + ONE barrier per plane (sW double-buffered; the build
// reads only the PREVIOUS plane from LDS -- current-plane values ride in regs
// for both pass 1 and pass 2).
__global__ __launch_bounds__(256, 7)
void nh_fused_kernel(const float* __restrict__ P, float* __restrict__ out) {
    const int tid = threadIdx.x;
    const int tx  = tid & 15;        // lane within DPP row == w within halo
    const int ty  = tid >> 4;        // h within tile
    const int w0  = blockIdx.x * TW;
    const int h0  = blockIdx.y * TH;
    const int ds  = blockIdx.z * CD;
    const int de  = min(ds + CD, OD);

    __shared__ f4 sraw[2][19][18];   // raw y_pred ring, rows h0-1..h0+17, cols w0-1..w0+15
    __shared__ h8 sW[2][18][16];     // w-summed diffs, double-buffered by t parity
    __shared__ h2 sWB[2][18][16];    // w-summed {Wd2, 0}
    __shared__ float wsum[4];

    // ---- loop-invariant geometry (hoisted out of the z loop) ----
    // primary halo point (ty, tx)
    const int hp_p = h0 - 1 + ty;
    const int wp_p = w0 - 1 + tx;
    const bool in_raw_p  = (hp_p >= 0) & (hp_p < DIM) & (wp_p >= 0) & (wp_p < DIM);
    const bool in_diff_p = (hp_p >= 0) & (hp_p < OD)  & (wp_p >= 0) & (wp_p < OD);
    const int base_p = hp_p * DIM + wp_p;

    // leftover halo point: tids 0..47 -> rows 16..18 x cols 0..15 (so pass-2
    // threads 0..31 own exactly the rows-16/17 points they build);
    // tids 48..66 -> col 16, rows 0..18.
    int hh_l, ww_l;
    if (tid < 48) { hh_l = 16 + (tid >> 4); ww_l = tid & 15; }
    else          { hh_l = tid - 48;        ww_l = 16; }
    const bool has_l = (tid < 67);
    const int hp_l = h0 - 1 + hh_l;
    const int wp_l = w0 - 1 + ww_l;
    const bool in_raw_l  = has_l & (hp_l >= 0) & (hp_l < DIM) & (wp_l >= 0) & (wp_l < DIM);
    const bool in_diff_l = (tid < 32) & (hp_l >= 0) & (hp_l < OD) & (wp_l >= 0) & (wp_l < OD);
    const int base_l = hp_l * DIM + wp_l;

    const bool valid = (tx < TW) && (w0 + tx < OD) && (h0 + ty < OD);

    h8 a0 = (h8)0, a1 = (h8)0, a2 = (h8)0;
    h2 b0 = (h2)0, b1 = (h2)0, b2 = (h2)0;
    f4 cur_p = (f4)0, prev_p = (f4)0;    // this thread's raw value at primary point, planes t / t-1
    f4 cur_l = (f4)0, prev_l = (f4)0;    // same for leftover point
    float acc = 0.f;

    // preload plane t0 = ds-1
    {
        const int t0 = ds - 1;
        if (t0 >= 0) {
            cur_p = ld3(P, t0 * PLANE + base_p, in_raw_p);
            cur_l = ld3(P, t0 * PLANE + base_l, in_raw_l);
        }
    }

    for (int t = ds - 1; t <= de + 1; ++t) {
        const int cb = t & 1, pb = cb ^ 1;

        // (1) prefetch plane t+1 into regs (consumed NEXT iteration ->
        //     HBM latency hides under this iteration's build+tap+energy)
        f4 nxt_p = (f4)0, nxt_l = (f4)0;
        {
            const int tn = t + 1;
            if ((tn < DIM) & (tn <= de + 1)) {       // wave-uniform
                nxt_p = ld3(P, tn * PLANE + base_p, in_raw_p);
                nxt_l = ld3(P, tn * PLANE + base_l, in_raw_l);
            }
        }

        // (2) stage raw plane t into LDS ring (values already in regs)
        sraw[cb][ty][tx] = cur_p;
        if (has_l) sraw[cb][hh_l][ww_l] = cur_l;

        // (3) build w-summed diff plane p = t-1 into sW[cb]
        //     reads ONLY sraw[pb] (synced last iteration) + registers
        const bool built = (t >= ds) & (t - 1 >= 0) & (t - 1 < OD);   // wave-uniform

        {   // pass 1: rows 0..15
            h8 sa = (h8)0; h2 sb = (h2)0;
            if (built) {
                h8 va = (h8)0; h2 vb = (h2)0;
                if (in_diff_p) {
                    const f4 c  = prev_p;                  // (p, hp, wp)
                    const f4 cw = sraw[pb][ty][tx + 1];    // (p, hp, wp+1)
                    const f4 ch = sraw[pb][ty + 1][tx];    // (p, hp+1, wp)
                    const f4 cd = cur_p;                   // (p+1, hp, wp)
                    make_diff(c, cw, ch, cd, va, vb);
                }
                wsum3(va, vb);                             // all lanes participate
                sa = va; sb = vb;
            }
            sW[cb][ty][tx] = sa; sWB[cb][ty][tx] = sb;
        }
        if (tid < 32) {  // pass 2: rows 16,17 (leftover regs ARE these points)
            h8 sa = (h8)0; h2 sb = (h2)0;
            if (built) {
                h8 va = (h8)0; h2 vb = (h2)0;
                if (in_diff_l) {
                    const f4 c  = prev_l;
                    const f4 cw = sraw[pb][hh_l][ww_l + 1];
                    const f4 ch = sraw[pb][hh_l + 1][ww_l];
                    const f4 cd = cur_l;
                    make_diff(c, cw, ch, cd, va, vb);
                }
                wsum3(va, vb);
                sa = va; sb = vb;
            }
            sW[cb][hh_l][ww_l] = sa; sWB[cb][hh_l][ww_l] = sb;
        }

        __syncthreads();   // the ONLY barrier per plane

        // (4) h-window 3-tap, rotate z-ring, emit d = t-2
        a0 = a1; a1 = a2; b0 = b1; b1 = b2;
        {
            const int cc = (tx + 1) & 15;   // symmetric w-sum center; tx>=14 masked by valid
            a2 = sW[cb][ty][cc] + sW[cb][ty + 1][cc] + sW[cb][ty + 2][cc];
            b2 = sWB[cb][ty][cc] + sWB[cb][ty + 1][cc] + sWB[cb][ty + 2][cc];
        }

        const int d = t - 2;
        if (valid && d >= ds && d < de) {
            const h8 FA = a0 + a1 + a2;
            const h2 FB = b0 + b1 + b2;
            const float inv27 = 1.f / 27.f;
            const float dydx = (float)FA[0] * inv27, dxdx = (float)FA[1] * inv27, dzdx = (float)FA[2] * inv27;
            const float dydy = (float)FA[3] * inv27, dxdy = (float)FA[4] * inv27, dzdy = (float)FA[5] * inv27;
            const float dydz = (float)FA[6] * inv27, dxdz = (float)FA[7] * inv27, dzdz = (float)FB[0] * inv27;
            const float a = dxdx + 1.f, e = dydy + 1.f, iN = dzdz + 1.f;
            const float J = a * (e * iN - dydz * dzdy)
                          - dxdy * (dydx * iN - dydz * dzdx)
                          + dxdz * (dydx * dzdy - e * dzdx);
            const float Tr = a * a + dxdy * dxdy + dxdz * dxdz
                           + dydx * dydx + e * e + dydz * dydz
                           + dzdx * dzdx + dzdy * dzdy + iN * iN;
            const float stretch = Tr * expf(1.f - J) - 3.f;
            const float vol = (J - 1.f) * (J - 1.f);
            // mu=1,lam=5 -> U = (1/12)*stretch + (15/31)*vol (verified exact)
            acc += 0.0833333358f * stretch + 0.4838709677f * vol;
        }

        prev_p = cur_p; cur_p = nxt_p;
        prev_l = cur_l; cur_l = nxt_l;
    }

    // mean scaling (191^3)
    acc *= (1.f / 6967871.f);

    // wave reduce (64 lanes), then block reduce, one atomic per block
    #pragma unroll
    for (int off = 32; off > 0; off >>= 1) acc += __shfl_down(acc, off, 64);
    if ((tid & 63) == 0) wsum[tid >> 6] = acc;
    __syncthreads();
    if (tid == 0) {
        atomicAdd(out, wsum[0] + wsum[1] + wsum[2] + wsum[3]);
    }
}

extern "C" void kernel_launch(void* const* d_in, const int* in_sizes, int n_in,
                              void* d_out, int out_size, void* d_ws, size_t ws_size,
                              hipStream_t stream) {
    const float* y_pred = (const float*)d_in[0];
    float* out = (float*)d_out;

    // d_out is poisoned 0xAA before every timed launch — zero it (graph-capturable).
    hipMemsetAsync(out, 0, sizeof(float), stream);

    dim3 grid(NBW, NBH, NCH);
    nh_fused_kernel<<<grid, 256, 0, stream>>>(y_pred, out);
}